// Round 17
// baseline (185.106 us; speedup 1.0000x reference)
//
#include <hip/hip_runtime.h>
#include <hip/hip_bf16.h>

#define SL_DIM  12    // H*DC = 4*3
#define CAPS    896   // per-bin edge capacity; bin ~ Poisson(512), +17 sigma

using short8 = __attribute__((ext_vector_type(8))) short;   // 8 bf16 (4 VGPR)
using f32x4  = __attribute__((ext_vector_type(4))) float;   // MFMA C/D

// round-to-nearest-even fp32 -> bf16
__device__ __forceinline__ unsigned f2bf(float f) {
    union { float f; unsigned u; } x; x.f = f;
    const unsigned r = x.u + 0x7FFFu + ((x.u >> 16) & 1u);
    return r >> 16;
}
__device__ __forceinline__ float bf2f(unsigned u) {
    union { unsigned u; float f; } x; x.u = u << 16;
    return x.f;
}

// ===========================================================================
// R14..R17: fine-binned sort (1563 bins of 32 dst each) with the final
// grouping fused INTO the node kernel (in-LDS counting sort), eliminating
// binsort, sorted2, cursor and rowstart. R13 lesson: launch-count alone is
// not the lever (R9 176.9 vs R13 175.8); the unmeasured mid-pipeline mass is.
// Pipeline (5 launches):
//   K1 hist_qkv: heterogeneous (qkv MFMA role + 1563-bin hist role),
//       table BLOCK-MAJOR T[g][bin] so both hist writes and scatter cursor
//       loads are coalesced.
//   K2 colsum:  binsum[b] = sum of column b (strided L2 reads, balanced)
//   K3 colscan: base from binsum[<b] + exclusive scan of own column
//   K4 scatter: 1563 LDS cursors, group edges by dst>>5 into sorted1
//   K5 nodeseg: block = bin; LDS counting sort of ~512 edges by dst&31,
//       then 4 waves x 8 nodes with edge lists served from LDS (broadcast).
//       Per-edge math byte-identical to R13's node_kernel.
// ===========================================================================

// ---------------------------------------------------------------------------
// K1: heterogeneous hist + qkv.
// ---------------------------------------------------------------------------
__global__ __launch_bounds__(256) void hist_qkv_kernel(
    const float* __restrict__ h,
    const float* __restrict__ Wq, const float* __restrict__ bq,
    const float* __restrict__ Wk, const float* __restrict__ bk,
    const float* __restrict__ Wv, const float* __restrict__ bv,
    float* __restrict__ Q, unsigned* __restrict__ KV, int N,
    const int* __restrict__ src, const int* __restrict__ dst,
    unsigned* __restrict__ packed0, unsigned* __restrict__ T,
    int E, int NB, int NSEG)
{
    __shared__ short8 sB[2][12][2][64];   // 48 KB (qkv); hist aliases 6.3 KB

    const int bi  = (int)blockIdx.x;
    const int tid = threadIdx.x;

    if (bi % 5 != 0) {
        // ---------------- hist role (1563 bins) ----------------
        const int g = bi - bi / 5 - 1;        // 0..783 (spares guarded)
        if (g >= NB) return;
        unsigned* lh = (unsigned*)&sB[0][0][0][0];
        for (int i = tid; i < NSEG; i += 256) lh[i] = 0;
        __syncthreads();
        const int e0 = g * 1024 + tid;
#pragma unroll
        for (int j = 0; j < 4; ++j) {
            const int e = e0 + j * 256;
            if (e < E) {
                const unsigned d = (unsigned)dst[e];
                const unsigned v = (d << 16) | (unsigned)src[e];
                packed0[e] = v;
                atomicAdd(&lh[d >> 5], 1u);
            }
        }
        __syncthreads();
        // block-major table: block g writes a contiguous row (coalesced)
        for (int i = tid; i < NSEG; i += 256)
            T[(size_t)g * NSEG + i] = lh[i];
        return;
    }

    // ---------------- qkv role (verified R12/R13) ----------------
    const int qb = bi / 5;                    // 0..195

    {
        unsigned* sBw = (unsigned*)&sB[0][0][0][0];
        for (int i = tid; i < 6144; i += 256) {
            const int d = i & 3;
            const int l = (i >> 2) & 63;
            const int s = (i >> 8) & 1;
            const int t = i >> 9;
            const int m = t >> 2;
            const int c = (t & 3) * 16 + (l & 15);
            const int k = s * 32 + ((l >> 4) << 3) + (d << 1);
            const float* Wm = (m == 0) ? Wq : (m == 1) ? Wk : Wv;
            const float w0 = Wm[k * 64 + c];
            const float w1 = Wm[(k + 1) * 64 + c];
            const unsigned h0 = f2bf(w0), h1 = f2bf(w1);
            const unsigned l0 = f2bf(w0 - bf2f(h0));
            const unsigned l1 = f2bf(w1 - bf2f(h1));
            const int base = ((t * 2 + s) * 64 + l) * 4 + d;
            sBw[base]        = h0 | (h1 << 16);
            sBw[6144 + base] = l0 | (l1 << 16);
        }
    }
    __syncthreads();

    const int lane = tid & 63;
    const int wid  = tid >> 6;
    const int c16  = lane & 15;
    const int gk   = lane >> 4;

    float bqc[4], bkc[4], bvc[4];
#pragma unroll
    for (int tt = 0; tt < 4; ++tt) {
        bqc[tt] = bq[tt * 16 + c16];
        bkc[tt] = bk[tt * 16 + c16];
        bvc[tt] = bv[tt * 16 + c16];
    }

    const int job0 = (qb * 4 + wid) * 4;

#define SPLIT8(V0, V1, HI, LO)                                            \
    {                                                                     \
        const float _f[8] = {V0.x, V0.y, V0.z, V0.w,                      \
                             V1.x, V1.y, V1.z, V1.w};                     \
        _Pragma("unroll")                                                 \
        for (int _j = 0; _j < 8; ++_j) {                                  \
            const unsigned _hh = f2bf(_f[_j]);                            \
            HI[_j] = (short)_hh;                                          \
            LO[_j] = (short)(unsigned short)f2bf(_f[_j] - bf2f(_hh));     \
        }                                                                 \
    }

    for (int j = 0; j < 4; ++j) {
        const int rowBase = (job0 + j) * 16;
        if (rowBase >= N) break;           // N%16==0: jobs are full

        const float4* hr = (const float4*)(h + (size_t)(rowBase + c16) * 64 + (gk << 3));
        const float4 a00 = hr[0], a01 = hr[1];
        const float4 a10 = hr[8], a11 = hr[9];

        short8 Ah0, Al0, Ah1, Al1;
        SPLIT8(a00, a01, Ah0, Al0)
        SPLIT8(a10, a11, Ah1, Al1)

        f32x4 acc[12];
#pragma unroll
        for (int t = 0; t < 12; ++t) acc[t] = (f32x4){0.f, 0.f, 0.f, 0.f};

#pragma unroll
        for (int t = 0; t < 12; ++t) {
#pragma unroll
            for (int s = 0; s < 2; ++s) {
                const short8 bh = sB[0][t][s][lane];
                const short8 bl = sB[1][t][s][lane];
                const short8 ah = s ? Ah1 : Ah0;
                const short8 al = s ? Al1 : Al0;
                acc[t] = __builtin_amdgcn_mfma_f32_16x16x32_bf16(ah, bh, acc[t], 0, 0, 0);
                acc[t] = __builtin_amdgcn_mfma_f32_16x16x32_bf16(ah, bl, acc[t], 0, 0, 0);
                acc[t] = __builtin_amdgcn_mfma_f32_16x16x32_bf16(al, bh, acc[t], 0, 0, 0);
            }
        }

#pragma unroll
        for (int reg = 0; reg < 4; ++reg) {
            const int row = rowBase + (gk << 2) + reg;
            float*    qrow  = Q  + (size_t)row * 64;
            unsigned* kvrow = KV + (size_t)row * 64;
#pragma unroll
            for (int tt = 0; tt < 4; ++tt) {
                qrow[tt * 16 + c16] = acc[tt][reg] + bqc[tt];
                const unsigned kb = f2bf(acc[4 + tt][reg] + bkc[tt]);
                const unsigned vb = f2bf(acc[8 + tt][reg] + bvc[tt]);
                kvrow[tt * 16 + c16] = (vb << 16) | kb;
            }
        }
    }
#undef SPLIT8
}

// ---------------------------------------------------------------------------
// K2: per-bin total. Block b sums column b of T (stride-NSEG L2 reads).
// ---------------------------------------------------------------------------
__global__ __launch_bounds__(256) void colsum_kernel(
    const unsigned* __restrict__ T, unsigned* __restrict__ binsum,
    int NB, int NSEG)
{
    __shared__ unsigned ws[4];
    const int b = blockIdx.x, tid = threadIdx.x, lane = tid & 63, w = tid >> 6;
    unsigned s = 0;
    for (int g = tid; g < NB; g += 256) s += T[(size_t)g * NSEG + b];
#pragma unroll
    for (int off = 32; off; off >>= 1) s += __shfl_down(s, off);
    if (lane == 0) ws[w] = s;
    __syncthreads();
    if (tid == 0) binsum[b] = ws[0] + ws[1] + ws[2] + ws[3];
}

// ---------------------------------------------------------------------------
// K3: per-bin column scan with base from binsum. Race-free: block b reads
// binsum[<b], reads/writes only its own column. Scan order = g ascending.
// ---------------------------------------------------------------------------
__global__ __launch_bounds__(256) void colscan_kernel(
    unsigned* __restrict__ T, const unsigned* __restrict__ binsum,
    int NB, int NSEG)
{
    __shared__ unsigned wsum[4];
    __shared__ unsigned sbase;
    const int b = blockIdx.x, tid = threadIdx.x, lane = tid & 63, w = tid >> 6;

    unsigned contrib = 0;
    for (int i = tid; i < b; i += 256) contrib += binsum[i];
#pragma unroll
    for (int off = 32; off; off >>= 1) contrib += __shfl_down(contrib, off);
    if (lane == 0) wsum[w] = contrib;
    __syncthreads();
    if (tid == 0) sbase = wsum[0] + wsum[1] + wsum[2] + wsum[3];
    __syncthreads();

    unsigned run = sbase;
    for (int c0 = 0; c0 < NB; c0 += 256) {
        const int g = c0 + tid;
        const unsigned v = (g < NB) ? T[(size_t)g * NSEG + b] : 0u;
        unsigned x = v;
#pragma unroll
        for (int off = 1; off < 64; off <<= 1) {
            const unsigned u = __shfl_up(x, off);
            if (lane >= off) x += u;
        }
        if (lane == 63) wsum[w] = x;
        __syncthreads();
        unsigned wb = 0;
#pragma unroll
        for (int k = 0; k < 4; ++k) if (k < w) wb += wsum[k];
        const unsigned tot = wsum[0] + wsum[1] + wsum[2] + wsum[3];
        if (g < NB) T[(size_t)g * NSEG + b] = run + wb + (x - v);
        run += tot;
        __syncthreads();   // protect wsum for next chunk
    }
}

// ---------------------------------------------------------------------------
// K4: scatter into 1563 bin segments via LDS cursors (no global atomics).
// Cursor load is a contiguous row of T (block-major) -> coalesced.
// ---------------------------------------------------------------------------
__global__ __launch_bounds__(256) void scatter_kernel(
    const unsigned* __restrict__ packed0, const unsigned* __restrict__ T,
    unsigned* __restrict__ sorted1, int E, int NB, int NSEG)
{
    __shared__ unsigned lcur[1600];
    const int g = blockIdx.x, tid = threadIdx.x;
    for (int i = tid; i < NSEG; i += 256) lcur[i] = T[(size_t)g * NSEG + i];
    __syncthreads();
    const int e0 = g * 1024 + tid;
#pragma unroll
    for (int j = 0; j < 4; ++j) {
        const int e = e0 + j * 256;
        if (e < E) {
            const unsigned v = packed0[e];
            const unsigned p = atomicAdd(&lcur[v >> 21], 1u);   // LDS atomic
            sorted1[p] = v;
        }
    }
}

// ---------------------------------------------------------------------------
// K5: fused in-LDS grouping + node math. Block = bin (32 dst, ~512 edges).
// Segment bounds from scanned T: rb = T[b] (g=0 entry), re = T[b+1].
// Two passes over the L2-hot segment: count by dst&31, then LDS scatter.
// Then 4 waves x 8 nodes, per-edge math identical to R13's node_kernel.
// ---------------------------------------------------------------------------
__global__ __launch_bounds__(256) void nodeseg_kernel(
    const float* __restrict__ Q, const unsigned* __restrict__ KV,
    const float* __restrict__ s_l,
    const unsigned* __restrict__ T, const unsigned* __restrict__ sorted1,
    float* __restrict__ out, int N, int E, int NSEG)
{
    __shared__ unsigned eSort[CAPS];
    __shared__ unsigned subcnt[32], substart[32], subcur[32];

    const int b   = (int)blockIdx.x;
    const int tid = threadIdx.x;

    const unsigned rb = T[b];
    const unsigned re = (b + 1 < NSEG) ? T[b + 1] : (unsigned)E;
    int cnt = (int)(re - rb);
    if (cnt > CAPS) cnt = CAPS;   // P ~ 0 (Poisson(512) vs 896)

    if (tid < 32) subcnt[tid] = 0;
    __syncthreads();
    for (int i = tid; i < cnt; i += 256)
        atomicAdd(&subcnt[(sorted1[rb + i] >> 16) & 31u], 1u);
    __syncthreads();
    if (tid < 32) {
        const unsigned x = subcnt[tid];
        unsigned v = x;
#pragma unroll
        for (int off = 1; off < 32; off <<= 1) {
            const unsigned u = __shfl_up(v, off);
            if ((tid & 63) >= off) v += u;
        }
        substart[tid] = v - x;
        subcur[tid]   = v - x;
    }
    __syncthreads();
    for (int i = tid; i < cnt; i += 256) {
        const unsigned v = sorted1[rb + i];
        const unsigned p = atomicAdd(&subcur[(v >> 16) & 31u], 1u);
        if (p < CAPS) eSort[p] = v;
    }
    __syncthreads();

    // ---- node processing: wave w handles sub-nodes w, w+4, ..., w+28 ----
    const int lane = tid & 63;
    const int wid  = tid >> 6;
    const int e2   = lane >> 4;
    const int hq   = lane & 15;
    const int head = hq >> 2;
    const int quad = hq & 3;

    for (int j = wid; j < 32; j += 4) {
        const int node = b * 32 + j;
        if (node >= N) continue;           // no syncthreads below: safe

        const int deg = (int)subcnt[j];
        const int st  = (int)substart[j];

        const float4 qv = *(const float4*)(Q + (size_t)node * 64 + (hq << 2));
        const float slv = (quad < 3) ? s_l[(size_t)node * SL_DIM + head * 3 + quad] : 0.f;

        float4 accV = make_float4(0.f, 0.f, 0.f, 0.f);
        float zs = 0.f;

        const int ng = (deg + 3) >> 2;
#pragma unroll 2
        for (int i = 0; i < ng; ++i) {
            const int slot  = (i << 2) + e2;
            const bool valid = slot < deg;
            const int sidx  = (int)(eSort[st + (valid ? slot : 0)] & 0xFFFFu);

            const uint4 kv = *(const uint4*)(KV + (size_t)sidx * 64 + (hq << 2));
            const float a  = (quad < 3) ? s_l[(size_t)sidx * SL_DIM + head * 3 + quad] : 0.f;

            float dt = __uint_as_float(kv.x << 16) * qv.x
                     + __uint_as_float(kv.y << 16) * qv.y
                     + __uint_as_float(kv.z << 16) * qv.z
                     + __uint_as_float(kv.w << 16) * qv.w;
            const float df = a - slv;
            float ds = df * df;

            dt += __shfl_xor(dt, 1, 4);
            dt += __shfl_xor(dt, 2, 4);
            ds += __shfl_xor(ds, 1, 4);
            ds += __shfl_xor(ds, 2, 4);

            const float sc = fminf(fmaxf(dt * 0.25f, -5.f), 5.f);
            float score = __expf(sc);
            score = valid ? score : 0.f;
            const float w    = __expf(-ds * ds);
            const float news = score * w;
            zs += score;

            accV.x += __uint_as_float(kv.x & 0xFFFF0000u) * news;
            accV.y += __uint_as_float(kv.y & 0xFFFF0000u) * news;
            accV.z += __uint_as_float(kv.z & 0xFFFF0000u) * news;
            accV.w += __uint_as_float(kv.w & 0xFFFF0000u) * news;
        }

#pragma unroll
        for (int m = 16; m <= 32; m <<= 1) {
            accV.x += __shfl_xor(accV.x, m);
            accV.y += __shfl_xor(accV.y, m);
            accV.z += __shfl_xor(accV.z, m);
            accV.w += __shfl_xor(accV.w, m);
            zs     += __shfl_xor(zs, m);
        }

        if (e2 == 0) {
            const float inv = (zs > 0.f) ? (1.f / zs) : 1.f;
            float4 o;
            o.x = accV.x * inv; o.y = accV.y * inv;
            o.z = accV.z * inv; o.w = accV.w * inv;
            *(float4*)(out + (size_t)node * 64 + (hq << 2)) = o;
        }
    }
}

extern "C" void kernel_launch(void* const* d_in, const int* in_sizes, int n_in,
                              void* d_out, int out_size, void* d_ws, size_t ws_size,
                              hipStream_t stream) {
    const float* h   = (const float*)d_in[0];
    const float* s_l = (const float*)d_in[1];
    const float* Wq  = (const float*)d_in[2];
    const float* bq  = (const float*)d_in[3];
    const float* Wk  = (const float*)d_in[4];
    const float* bk  = (const float*)d_in[5];
    const float* Wv  = (const float*)d_in[6];
    const float* bv  = (const float*)d_in[7];
    const int*   src = (const int*)d_in[8];
    const int*   dst = (const int*)d_in[9];
    float* out = (float*)d_out;

    const int N = in_sizes[0] / 64;      // 50000
    const int E = in_sizes[8];           // 800000
    const int NB = (E + 1023) / 1024;    // 782 edge blocks
    const int NSEG = (N + 31) / 32;      // 1563 bins of 32 dst

    // workspace: Q | KV | packed0 | sorted1 | T (NB*NSEG) | binsum (NSEG)
    float*    Q       = (float*)d_ws;
    unsigned* KV      = (unsigned*)(Q + (size_t)N * 64);
    unsigned* packed0 = KV + (size_t)N * 64;
    unsigned* sorted1 = packed0 + E;
    unsigned* T       = sorted1 + E;
    unsigned* binsum  = T + (size_t)NB * NSEG;

    // 5 launches: {hist+qkv} -> colsum -> colscan -> scatter -> nodeseg
    const int QB = (N + 255) / 256;      // 196 qkv blocks
    hist_qkv_kernel<<<QB * 5, 256, 0, stream>>>(
        h, Wq, bq, Wk, bk, Wv, bv, Q, KV, N,
        src, dst, packed0, T, E, NB, NSEG);
    colsum_kernel<<<NSEG, 256, 0, stream>>>(T, binsum, NB, NSEG);
    colscan_kernel<<<NSEG, 256, 0, stream>>>(T, binsum, NB, NSEG);
    scatter_kernel<<<NB, 256, 0, stream>>>(packed0, T, sorted1, E, NB, NSEG);
    nodeseg_kernel<<<NSEG, 256, 0, stream>>>(Q, KV, s_l, T, sorted1,
                                             out, N, E, NSEG);
}

// Round 18
// 171.995 us; speedup vs baseline: 1.0762x; 1.0762x over previous
//
#include <hip/hip_runtime.h>
#include <hip/hip_bf16.h>

#define SL_DIM    12   // H*DC = 4*3

using short8 = __attribute__((ext_vector_type(8))) short;   // 8 bf16 (4 VGPR)
using f32x4  = __attribute__((ext_vector_type(4))) float;   // MFMA C/D

// round-to-nearest-even fp32 -> bf16
__device__ __forceinline__ unsigned f2bf(float f) {
    union { float f; unsigned u; } x; x.f = f;
    const unsigned r = x.u + 0x7FFFu + ((x.u >> 16) & 1u);
    return r >> 16;
}
__device__ __forceinline__ float bf2f(unsigned u) {
    union { unsigned u; float f; } x; x.u = u << 16;
    return x.f;
}

// ===========================================================================
// R18 = R13 verbatim (session-best measured: 175.8us). R17's fine-bin
// experiment regressed (185.1: nodeseg == node_kernel cost, but the 6x
// bigger bin table made the mid-pipeline ~20us more expensive).
// Session synthesis: four architectures (R0/R5/R9/R13) all land at 175+-1.
// Accounting closes: harness poison-fill 46 + node 45 (XCD-replicated
// random-src gather floor, FETCH ~134MB @ ~3TB/s) + hist_qkv 15 + sort ~16
// + ~6us x 7 launch boundaries ~= 175. This is the composite floor.
// Pipeline (6 launches): {hist+qkv} -> rowsum -> rowscan -> scatter ->
// binsort -> node. Every component individually measured-good.
// ===========================================================================

// ---------------------------------------------------------------------------
// K_A: heterogeneous hist + qkv (verified R12/R13).
// hist role: per-block LDS histogram of hi(dst) -> bin-major table + pack.
// qkv role: bf16 hi/lo split MFMA GEMM (D = Ahi*Bhi + Ahi*Blo + Alo*Bhi).
// ---------------------------------------------------------------------------
__global__ __launch_bounds__(256) void hist_qkv_kernel(
    const float* __restrict__ h,
    const float* __restrict__ Wq, const float* __restrict__ bq,
    const float* __restrict__ Wk, const float* __restrict__ bk,
    const float* __restrict__ Wv, const float* __restrict__ bv,
    float* __restrict__ Q, unsigned* __restrict__ KV, int N,
    const int* __restrict__ src, const int* __restrict__ dst,
    unsigned* __restrict__ packed0, unsigned* __restrict__ hist, int E, int NB)
{
    __shared__ short8 sB[2][12][2][64];   // 48 KB (qkv); hist aliases 1 KB

    const int bi  = (int)blockIdx.x;
    const int tid = threadIdx.x;

    if (bi % 5 != 0) {
        // ---------------- hist role ----------------
        const int g = bi - bi / 5 - 1;        // 0..783 (two spares skip)
        if (g >= NB) return;
        unsigned* lh = (unsigned*)&sB[0][0][0][0];
        lh[tid] = 0;
        __syncthreads();
        const int e0 = g * 1024 + tid;
#pragma unroll
        for (int j = 0; j < 4; ++j) {
            const int e = e0 + j * 256;
            if (e < E) {
                const unsigned d = (unsigned)dst[e];
                const unsigned v = (d << 16) | (unsigned)src[e];
                packed0[e] = v;
                atomicAdd(&lh[d >> 8], 1u);
            }
        }
        __syncthreads();
        hist[tid * NB + g] = lh[tid];         // bin-major table
        return;
    }

    // ---------------- qkv role ----------------
    const int qb = bi / 5;                    // 0..195

    {
        unsigned* sBw = (unsigned*)&sB[0][0][0][0];
        for (int i = tid; i < 6144; i += 256) {
            const int d = i & 3;
            const int l = (i >> 2) & 63;
            const int s = (i >> 8) & 1;
            const int t = i >> 9;
            const int m = t >> 2;
            const int c = (t & 3) * 16 + (l & 15);
            const int k = s * 32 + ((l >> 4) << 3) + (d << 1);
            const float* Wm = (m == 0) ? Wq : (m == 1) ? Wk : Wv;
            const float w0 = Wm[k * 64 + c];
            const float w1 = Wm[(k + 1) * 64 + c];
            const unsigned h0 = f2bf(w0), h1 = f2bf(w1);
            const unsigned l0 = f2bf(w0 - bf2f(h0));
            const unsigned l1 = f2bf(w1 - bf2f(h1));
            const int base = ((t * 2 + s) * 64 + l) * 4 + d;
            sBw[base]        = h0 | (h1 << 16);
            sBw[6144 + base] = l0 | (l1 << 16);
        }
    }
    __syncthreads();

    const int lane = tid & 63;
    const int wid  = tid >> 6;
    const int c16  = lane & 15;
    const int gk   = lane >> 4;

    float bqc[4], bkc[4], bvc[4];
#pragma unroll
    for (int tt = 0; tt < 4; ++tt) {
        bqc[tt] = bq[tt * 16 + c16];
        bkc[tt] = bk[tt * 16 + c16];
        bvc[tt] = bv[tt * 16 + c16];
    }

    const int job0 = (qb * 4 + wid) * 4;

#define SPLIT8(V0, V1, HI, LO)                                            \
    {                                                                     \
        const float _f[8] = {V0.x, V0.y, V0.z, V0.w,                      \
                             V1.x, V1.y, V1.z, V1.w};                     \
        _Pragma("unroll")                                                 \
        for (int _j = 0; _j < 8; ++_j) {                                  \
            const unsigned _hh = f2bf(_f[_j]);                            \
            HI[_j] = (short)_hh;                                          \
            LO[_j] = (short)(unsigned short)f2bf(_f[_j] - bf2f(_hh));     \
        }                                                                 \
    }

    for (int j = 0; j < 4; ++j) {
        const int rowBase = (job0 + j) * 16;
        if (rowBase >= N) break;           // N%16==0: jobs are full

        const float4* hr = (const float4*)(h + (size_t)(rowBase + c16) * 64 + (gk << 3));
        const float4 a00 = hr[0], a01 = hr[1];
        const float4 a10 = hr[8], a11 = hr[9];

        short8 Ah0, Al0, Ah1, Al1;
        SPLIT8(a00, a01, Ah0, Al0)
        SPLIT8(a10, a11, Ah1, Al1)

        f32x4 acc[12];
#pragma unroll
        for (int t = 0; t < 12; ++t) acc[t] = (f32x4){0.f, 0.f, 0.f, 0.f};

#pragma unroll
        for (int t = 0; t < 12; ++t) {
#pragma unroll
            for (int s = 0; s < 2; ++s) {
                const short8 bh = sB[0][t][s][lane];
                const short8 bl = sB[1][t][s][lane];
                const short8 ah = s ? Ah1 : Ah0;
                const short8 al = s ? Al1 : Al0;
                acc[t] = __builtin_amdgcn_mfma_f32_16x16x32_bf16(ah, bh, acc[t], 0, 0, 0);
                acc[t] = __builtin_amdgcn_mfma_f32_16x16x32_bf16(ah, bl, acc[t], 0, 0, 0);
                acc[t] = __builtin_amdgcn_mfma_f32_16x16x32_bf16(al, bh, acc[t], 0, 0, 0);
            }
        }

#pragma unroll
        for (int reg = 0; reg < 4; ++reg) {
            const int row = rowBase + (gk << 2) + reg;
            float*    qrow  = Q  + (size_t)row * 64;
            unsigned* kvrow = KV + (size_t)row * 64;
#pragma unroll
            for (int tt = 0; tt < 4; ++tt) {
                qrow[tt * 16 + c16] = acc[tt][reg] + bqc[tt];
                const unsigned kb = f2bf(acc[4 + tt][reg] + bkc[tt]);
                const unsigned vb = f2bf(acc[8 + tt][reg] + bvc[tt]);
                kvrow[tt * 16 + c16] = (vb << 16) | kb;
            }
        }
    }
#undef SPLIT8
}

// ---------------------------------------------------------------------------
// K2a (measured): per-bin total. Block = bin; row contiguous -> coalesced.
// ---------------------------------------------------------------------------
__global__ __launch_bounds__(256) void rowsum_kernel(
    const unsigned* __restrict__ hist, unsigned* __restrict__ binsum, int NB)
{
    __shared__ unsigned ws[4];
    const int bin = blockIdx.x, tid = threadIdx.x, lane = tid & 63, w = tid >> 6;
    unsigned s = 0;
    for (int i = tid; i < NB; i += 256) s += hist[(size_t)bin * NB + i];
#pragma unroll
    for (int off = 32; off; off >>= 1) s += __shfl_down(s, off);
    if (lane == 0) ws[w] = s;
    __syncthreads();
    if (tid == 0) binsum[bin] = ws[0] + ws[1] + ws[2] + ws[3];
}

// ---------------------------------------------------------------------------
// K2b (measured): per-bin row scan with base from binsum. Race-free:
// block bin reads binsum[<bin] and reads/writes only its own row.
// ---------------------------------------------------------------------------
__global__ __launch_bounds__(256) void rowscan_kernel(
    unsigned* __restrict__ hist, const unsigned* __restrict__ binsum, int NB)
{
    __shared__ unsigned wsum[4];
    __shared__ unsigned sbase;
    const int bin = blockIdx.x, tid = threadIdx.x, lane = tid & 63, w = tid >> 6;

    // base = sum of binsum[0..bin-1]
    unsigned contrib = (tid < bin) ? binsum[tid] : 0u;
#pragma unroll
    for (int off = 32; off; off >>= 1) contrib += __shfl_down(contrib, off);
    if (lane == 0) wsum[w] = contrib;
    __syncthreads();
    if (tid == 0) sbase = wsum[0] + wsum[1] + wsum[2] + wsum[3];
    __syncthreads();

    unsigned run = sbase;
    for (int c0 = 0; c0 < NB; c0 += 256) {
        const int i = c0 + tid;
        const unsigned v = (i < NB) ? hist[(size_t)bin * NB + i] : 0u;
        unsigned x = v;
#pragma unroll
        for (int off = 1; off < 64; off <<= 1) {
            const unsigned u = __shfl_up(x, off);
            if (lane >= off) x += u;
        }
        if (lane == 63) wsum[w] = x;
        __syncthreads();
        unsigned wb = 0;
#pragma unroll
        for (int k = 0; k < 4; ++k) if (k < w) wb += wsum[k];
        const unsigned tot = wsum[0] + wsum[1] + wsum[2] + wsum[3];
        if (i < NB) hist[(size_t)bin * NB + i] = run + wb + (x - v);
        run += tot;
        __syncthreads();   // protect wsum for next chunk
    }
}

__global__ __launch_bounds__(256) void scatter_kernel(
    const unsigned* __restrict__ packed0, const unsigned* __restrict__ hist,
    unsigned* __restrict__ sorted1, int E, int NB)
{
    __shared__ unsigned lcur[256];
    const int b = blockIdx.x, tid = threadIdx.x;
    lcur[tid] = hist[tid * NB + b];
    __syncthreads();
    const int e0 = b * 1024 + tid;
#pragma unroll
    for (int j = 0; j < 4; ++j) {
        const int e = e0 + j * 256;
        if (e < E) {
            const unsigned v = packed0[e];
            const unsigned p = atomicAdd(&lcur[v >> 24], 1u);   // LDS atomic
            sorted1[p] = v;
        }
    }
}

__global__ __launch_bounds__(256) void binsort_kernel(
    const unsigned* __restrict__ sorted1, const unsigned* __restrict__ hist,
    unsigned* __restrict__ sorted2, int* __restrict__ cursor,
    int* __restrict__ rowstart, int E, int NB, int N)
{
    __shared__ unsigned cnt[256], lcur[256], wsum[4];
    const int bin = blockIdx.x, tid = threadIdx.x, lane = tid & 63, w = tid >> 6;
    const unsigned rb = hist[bin * NB];
    const unsigned re = (bin < 255) ? hist[(bin + 1) * NB] : (unsigned)E;
    cnt[tid] = 0;
    __syncthreads();
    for (unsigned i = rb + tid; i < re; i += 256)
        atomicAdd(&cnt[(sorted1[i] >> 16) & 0xFFu], 1u);
    __syncthreads();
    // 256-bin exclusive scan (4 waves, shfl)
    const unsigned x = cnt[tid];
    unsigned v = x;
#pragma unroll
    for (int off = 1; off < 64; off <<= 1) {
        const unsigned u = __shfl_up(v, off);
        if (lane >= off) v += u;
    }
    if (lane == 63) wsum[w] = v;
    __syncthreads();
    unsigned wb = 0;
#pragma unroll
    for (int i = 0; i < 4; ++i) if (i < w) wb += wsum[i];
    const unsigned ex = wb + v - x;   // exclusive prefix of cnt[tid]
    lcur[tid] = ex;
    const int dstv = bin * 256 + tid;
    if (dstv < N) {
        cursor[dstv]   = (int)x;
        rowstart[dstv] = (int)(rb + ex);
    }
    __syncthreads();
    for (unsigned i = rb + tid; i < re; i += 256) {
        const unsigned vv = sorted1[i];
        const unsigned p  = rb + atomicAdd(&lcur[(vv >> 16) & 0xFFu], 1u);
        sorted2[p] = vv;
    }
}

// ---------------------------------------------------------------------------
// Node phase, edge-quad layout, reading the CSR (sorted2 + rowstart).
// One wave per node. lane = e2*16 + head*4 + quad.
// ---------------------------------------------------------------------------
__global__ __launch_bounds__(256) void node_kernel(
    const float* __restrict__ Q, const unsigned* __restrict__ KV,
    const float* __restrict__ s_l,
    const int* __restrict__ cursor, const int* __restrict__ rowstart,
    const unsigned* __restrict__ sorted2,
    float* __restrict__ out, int N)
{
    const int t = blockIdx.x * 256 + threadIdx.x;
    const int node = t >> 6;
    if (node >= N) return;
    const int lane = threadIdx.x & 63;
    const int e2   = lane >> 4;
    const int hq   = lane & 15;
    const int head = hq >> 2;
    const int quad = hq & 3;

    const int deg = cursor[node];
    const int rs  = rowstart[node];

    const float4 qv = *(const float4*)(Q + (size_t)node * 64 + (hq << 2));
    const float slv = (quad < 3) ? s_l[(size_t)node * SL_DIM + head * 3 + quad] : 0.f;

    const unsigned* lbase = sorted2 + rs;

    float4 accV = make_float4(0.f, 0.f, 0.f, 0.f);
    float zs = 0.f;

    const int ng = (deg + 3) >> 2;
#pragma unroll 2
    for (int i = 0; i < ng; ++i) {
        const int slot  = (i << 2) + e2;
        const bool valid = slot < deg;
        const int sidx  = (int)(lbase[valid ? slot : 0] & 0xFFFFu);

        const uint4 kv = *(const uint4*)(KV + (size_t)sidx * 64 + (hq << 2));
        const float a  = (quad < 3) ? s_l[(size_t)sidx * SL_DIM + head * 3 + quad] : 0.f;

        float dt = __uint_as_float(kv.x << 16) * qv.x
                 + __uint_as_float(kv.y << 16) * qv.y
                 + __uint_as_float(kv.z << 16) * qv.z
                 + __uint_as_float(kv.w << 16) * qv.w;
        const float df = a - slv;
        float ds = df * df;

        dt += __shfl_xor(dt, 1, 4);
        dt += __shfl_xor(dt, 2, 4);
        ds += __shfl_xor(ds, 1, 4);
        ds += __shfl_xor(ds, 2, 4);

        const float sc = fminf(fmaxf(dt * 0.25f, -5.f), 5.f);
        float score = __expf(sc);
        score = valid ? score : 0.f;
        const float w    = __expf(-ds * ds);
        const float news = score * w;
        zs += score;

        accV.x += __uint_as_float(kv.x & 0xFFFF0000u) * news;
        accV.y += __uint_as_float(kv.y & 0xFFFF0000u) * news;
        accV.z += __uint_as_float(kv.z & 0xFFFF0000u) * news;
        accV.w += __uint_as_float(kv.w & 0xFFFF0000u) * news;
    }

#pragma unroll
    for (int m = 16; m <= 32; m <<= 1) {
        accV.x += __shfl_xor(accV.x, m);
        accV.y += __shfl_xor(accV.y, m);
        accV.z += __shfl_xor(accV.z, m);
        accV.w += __shfl_xor(accV.w, m);
        zs     += __shfl_xor(zs, m);
    }

    if (e2 == 0) {
        const float inv = (zs > 0.f) ? (1.f / zs) : 1.f;
        float4 o;
        o.x = accV.x * inv; o.y = accV.y * inv;
        o.z = accV.z * inv; o.w = accV.w * inv;
        *(float4*)(out + (size_t)node * 64 + (hq << 2)) = o;
    }
}

extern "C" void kernel_launch(void* const* d_in, const int* in_sizes, int n_in,
                              void* d_out, int out_size, void* d_ws, size_t ws_size,
                              hipStream_t stream) {
    const float* h   = (const float*)d_in[0];
    const float* s_l = (const float*)d_in[1];
    const float* Wq  = (const float*)d_in[2];
    const float* bq  = (const float*)d_in[3];
    const float* Wk  = (const float*)d_in[4];
    const float* bk  = (const float*)d_in[5];
    const float* Wv  = (const float*)d_in[6];
    const float* bv  = (const float*)d_in[7];
    const int*   src = (const int*)d_in[8];
    const int*   dst = (const int*)d_in[9];
    float* out = (float*)d_out;

    const int N = in_sizes[0] / 64;   // 50000
    const int E = in_sizes[8];        // 800000
    const int NB = (E + 1023) / 1024; // 782 edge blocks

    // workspace: Q | KV | cursor | rowstart | packed0 | sorted1 | sorted2 |
    //            hist (256*NB) | binsum (256)
    float*    Q        = (float*)d_ws;
    unsigned* KV       = (unsigned*)(Q + (size_t)N * 64);
    int*      cursor   = (int*)(KV + (size_t)N * 64);
    int*      rowstart = cursor + N;
    unsigned* packed0  = (unsigned*)(rowstart + N);
    unsigned* sorted1  = packed0 + E;
    unsigned* sorted2  = sorted1 + E;
    unsigned* hist     = sorted2 + E;
    unsigned* binsum   = hist + (size_t)256 * NB;

    // 6 launches: {hist+qkv} -> rowsum -> rowscan -> scatter -> binsort -> node
    const int QB = (N + 255) / 256;   // 196 qkv blocks
    hist_qkv_kernel<<<QB * 5, 256, 0, stream>>>(
        h, Wq, bq, Wk, bk, Wv, bv, Q, KV, N,
        src, dst, packed0, hist, E, NB);
    rowsum_kernel<<<256, 256, 0, stream>>>(hist, binsum, NB);
    rowscan_kernel<<<256, 256, 0, stream>>>(hist, binsum, NB);
    scatter_kernel<<<NB, 256, 0, stream>>>(packed0, hist, sorted1, E, NB);
    binsort_kernel<<<256, 256, 0, stream>>>(sorted1, hist, sorted2,
                                            cursor, rowstart, E, NB, N);

    const long long nthreads = (long long)N * 64;
    node_kernel<<<(int)((nthreads + 255) / 256), 256, 0, stream>>>(
        Q, KV, s_l, cursor, rowstart, sorted2, out, N);
}